// Round 2
// baseline (153.018 us; speedup 1.0000x reference)
//
#include <hip/hip_runtime.h>

static constexpr int IMG  = 512;
static constexpr int TX   = 64;            // tile width  (output)
static constexpr int TY   = 64;            // tile height (output)
static constexpr int NTHR = 512;           // 8 waves/block; grid 1024 = 4 blocks/CU, all co-resident
static constexpr int SROWS = TY + 6;       // 70 staged rows (halo 3 each side)
static constexpr int LSTA  = 72;           // stage/A row stride (floats), 16B aligned
static constexpr int LSTB  = 68;           // step1-output row stride (floats), 16B aligned
static constexpr int NSTAGE = SROWS * (LSTA / 4);   // 70*18 = 1260 float4 items

__device__ __forceinline__ float gd_acc(float d, float acc) {
    const float t    = fmaf(d, d, 1.0f);
    const float rinv = __builtin_amdgcn_rcpf(t);
    const float e    = __builtin_amdgcn_exp2f(
                           -1.442695040888963f * __builtin_fabsf(d) * rinv);
    return fmaf(e, d, acc);
}

// One diffusion step over the LDS tile. Column meaning slides by the window
// offset each step so every LDS read stays 16B/8B aligned:
//   stage A col c <-> gx = tx0-4+c ; B col c <-> gx = tx0-2+c ;
//   step2-out A col c <-> gx = tx0-1+c ; step3 writes gout at gx = tx0+c0+i.
// Row anchor: stage row r <-> gy = ty0-3+r. B is stored with row offset -1.
template<int WOFF, int NR, int RLO, int NG, int ILST, int IROFF,
         int OLST, int OROFF, bool TO_GLOBAL>
__device__ __forceinline__ void diffuse_step(
    const float* __restrict__ prev, float* __restrict__ cur,
    const float* __restrict__ Wt, const float* __restrict__ bt,
    int xoff, int ty0, int tx0, int tid, float* __restrict__ gout)
{
    constexpr int NITEMS = NR * NG;
    for (int idx = tid; idx < NITEMS; idx += NTHR) {
        const int rr = idx / NG, j = idx - rr * NG;
        const int r  = RLO + rr, c0 = 4 * j;
        const float* base = prev + (r - 1 + IROFF) * ILST + c0;

        float L0[8], L1[8], L2[8];
        *(float4*)&L0[0] = *(const float4*)(base);
        *(float4*)&L1[0] = *(const float4*)(base + ILST);
        *(float4*)&L2[0] = *(const float4*)(base + 2 * ILST);
        if (WOFF) {
            *(float4*)&L0[4] = *(const float4*)(base + 4);
            *(float4*)&L1[4] = *(const float4*)(base + ILST + 4);
            *(float4*)&L2[4] = *(const float4*)(base + 2 * ILST + 4);
        } else {
            *(float2*)&L0[4] = *(const float2*)(base + 4);
            *(float2*)&L1[4] = *(const float2*)(base + ILST + 4);
            *(float2*)&L2[4] = *(const float2*)(base + 2 * ILST + 4);
        }

        float acc[4] = {0.f, 0.f, 0.f, 0.f};
#pragma unroll
        for (int k = 0; k < 8; ++k) {
            const float w0 = Wt[9*k+0], w1 = Wt[9*k+1], w2 = Wt[9*k+2];
            const float w3 = Wt[9*k+3], w4 = Wt[9*k+4], w5 = Wt[9*k+5];
            const float w6 = Wt[9*k+6], w7 = Wt[9*k+7], w8 = Wt[9*k+8];
            const float bk = bt[k];
#pragma unroll
            for (int i = 0; i < 4; ++i) {
                float d = bk;
                d = fmaf(w0, L0[WOFF+i],   d);
                d = fmaf(w1, L0[WOFF+i+1], d);
                d = fmaf(w2, L0[WOFF+i+2], d);
                d = fmaf(w3, L1[WOFF+i],   d);
                d = fmaf(w4, L1[WOFF+i+1], d);
                d = fmaf(w5, L1[WOFF+i+2], d);
                d = fmaf(w6, L2[WOFF+i],   d);
                d = fmaf(w7, L2[WOFF+i+1], d);
                d = fmaf(w8, L2[WOFF+i+2], d);
                acc[i] = gd_acc(d, acc[i]);
            }
        }

        float4 v;
        v.x = L1[WOFF+1] - acc[0] * 0.125f;
        v.y = L1[WOFF+2] - acc[1] * 0.125f;
        v.z = L1[WOFF+3] - acc[2] * 0.125f;
        v.w = L1[WOFF+4] - acc[3] * 0.125f;

        const int gy = ty0 - 3 + r;
        if (TO_GLOBAL) {
            // step3: rows/cols always fully interior to the image
            *(float4*)&gout[gy * IMG + tx0 + c0] = v;
        } else {
            // zero out-of-image pixels so the next step sees SAME zero padding
            const bool ry  = (unsigned)gy < (unsigned)IMG;
            const int  gx0 = xoff + c0;
            v.x = (ry && (unsigned)(gx0 + 0) < (unsigned)IMG) ? v.x : 0.f;
            v.y = (ry && (unsigned)(gx0 + 1) < (unsigned)IMG) ? v.y : 0.f;
            v.z = (ry && (unsigned)(gx0 + 2) < (unsigned)IMG) ? v.z : 0.f;
            v.w = (ry && (unsigned)(gx0 + 3) < (unsigned)IMG) ? v.w : 0.f;
            *(float4*)&cur[(r + OROFF) * OLST + c0] = v;
        }
    }
}

// All 3 diffusion steps fused. 64x64 output tile, 512 threads (8 waves).
// LDS: A 70x72 (20160 B) + B 68x68+pad (18528 B) = 38688 B -> 4 blocks/CU,
// grid(8,8,16)=1024 blocks = exactly 4/CU: everything co-resident, no tail.
__global__ __launch_bounds__(NTHR, 8) void deep_ad_fused512(
    const float* __restrict__ x, const float* __restrict__ W,
    const float* __restrict__ b, float* __restrict__ out)
{
    __shared__ float A [SROWS * LSTA];          // 5040 floats
    __shared__ float Bs[(TY + 4) * LSTB + 8];   // 4632 floats (pad: step2 tail-read)

    const int tid = threadIdx.x;
    const int tx0 = blockIdx.x * TX;
    const int ty0 = blockIdx.y * TY;
    const float* xin  = x   + (size_t)blockIdx.z * (IMG * IMG);
    float*       gout = out + (size_t)blockIdx.z * (IMG * IMG);

    // ---- stage input tile (zeros outside image == SAME padding) ----
    {
        float4 sv[3];
#pragma unroll
        for (int q = 0; q < 3; ++q) {
            const int item = tid + NTHR * q;
            float4 v = {0.f, 0.f, 0.f, 0.f};
            if (item < NSTAGE) {
                const int rr = item / 18, j = item - rr * 18;
                const int gy = ty0 - 3 + rr;
                const int gx = tx0 - 4 + 4 * j;   // float4 groups fully in or out
                if ((unsigned)gy < (unsigned)IMG && (unsigned)gx < (unsigned)IMG)
                    v = *(const float4*)(xin + gy * IMG + gx);
            }
            sv[q] = v;
        }
#pragma unroll
        for (int q = 0; q < 3; ++q) {
            const int item = tid + NTHR * q;
            if (item < NSTAGE) *(float4*)&A[item * 4] = sv[q];
        }
    }
    __syncthreads();

    // step1: A rows 1..68 -> B (68 rows x 68 cols), step2: B -> A rows 2..67,
    // step3: A rows 3..66 -> global 64x64 tile.
    diffuse_step<1, TY + 4, 1, 17, LSTA,  0, LSTB, -1, false>(
        A,  Bs, W,       b,      tx0 - 2, ty0, tx0, tid, nullptr);
    __syncthreads();
    diffuse_step<0, TY + 2, 2, 17, LSTB, -1, LSTA,  0, false>(
        Bs, A,  W + 72,  b + 8,  tx0 - 1, ty0, tx0, tid, nullptr);
    __syncthreads();
    diffuse_step<0, TY,     3, 16, LSTA,  0, 0,     0, true >(
        A, nullptr, W + 144, b + 16, 0, ty0, tx0, tid, gout);
}

extern "C" void kernel_launch(void* const* d_in, const int* in_sizes, int n_in,
                              void* d_out, int out_size, void* d_ws, size_t ws_size,
                              hipStream_t stream)
{
    const float* x = (const float*)d_in[0];
    const float* W = (const float*)d_in[1];  // [3,8,1,3,3]
    const float* b = (const float*)d_in[2];  // [3,8]
    float* out = (float*)d_out;
    const int N = in_sizes[0] / (IMG * IMG); // 16

    dim3 grid(IMG / TX, IMG / TY, N);        // (8, 8, 16) = 1024 blocks
    deep_ad_fused512<<<grid, NTHR, 0, stream>>>(x, W, b, out);
}

// Round 3
// 133.748 us; speedup vs baseline: 1.1441x; 1.1441x over previous
//
#include <hip/hip_runtime.h>

static constexpr int IMG   = 512;
static constexpr int TX    = 64;    // output tile width
static constexpr int TY    = 32;    // output tile height
static constexpr int NTHR  = 256;   // 4 waves/block
static constexpr int LSTA  = 72;    // A row stride (floats), 16B aligned
static constexpr int LSTB  = 68;    // B row stride (floats), 16B aligned
static constexpr int AROWS = 36;    // A holds orig stage rows 1..36 (rows 0/37 read from global)
static constexpr int NSTAGE = AROWS * (LSTA / 4);   // 648 float4 items
// LDS: A 36*72*4 = 10368 B, B (36*68+2)*4 = 9800 B -> 20168 B (~20224 padded)
// -> 8 blocks/CU * 4 waves = 32 waves/CU, grid 2048 fully co-resident, no tail.

__device__ __forceinline__ float gd_acc(float d, float acc) {
    const float t    = fmaf(d, d, 1.0f);
    const float rinv = __builtin_amdgcn_rcpf(t);
    const float e    = __builtin_amdgcn_exp2f(
                           -1.442695040888963f * __builtin_fabsf(d) * rinv);
    return fmaf(e, d, acc);
}

// 8 floats from global with per-float4 OOB predication (zeros = SAME padding).
__device__ __forceinline__ void ldg8(float* L, const float* __restrict__ img,
                                     int gy, int gx0) {
    float4 a = {0.f,0.f,0.f,0.f}, b = {0.f,0.f,0.f,0.f};
    if ((unsigned)gy < (unsigned)IMG) {
        const float* p = img + gy * IMG;
        if ((unsigned)gx0       < (unsigned)IMG) a = *(const float4*)(p + gx0);
        if ((unsigned)(gx0 + 4) < (unsigned)IMG) b = *(const float4*)(p + gx0 + 4);
    }
    *(float4*)&L[0] = a; *(float4*)&L[4] = b;
}

// Coordinate system (per block): stage col c <-> gx = tx0-4+c, stage row r
// (orig) <-> gy = ty0-3+r. A[j] = orig row j+1. B col c <-> gx = tx0-2+c,
// B[j] = step1-out row j+1. Step2 out col c <-> gx = tx0-1+c, stored A[r-1].
template<int WOFF, int NR, int RLO, int NG, int ILST, int OLST,
         bool HALOG, bool TO_GLOBAL>
__device__ __forceinline__ void diffuse_step(
    const float* __restrict__ prev, float* __restrict__ cur,
    const float* __restrict__ Wt, const float* __restrict__ bt,
    const float* __restrict__ xin, int xoff, int ty0, int tx0, int tid,
    float* __restrict__ gout)
{
    constexpr int NITEMS = NR * NG;
    for (int idx = tid; idx < NITEMS; idx += NTHR) {
        const int rr = idx / NG, j = idx - rr * NG;
        const int r  = RLO + rr, c0 = 4 * j;

        float L0[8], L1[8], L2[8];
        if (HALOG) {
            // step1: A holds orig rows 1..36; rows 0/37 come from global.
            const float* bc = prev + (r - 1) * ILST + c0;   // orig row r
            *(float4*)&L1[0] = *(const float4*)(bc);
            *(float4*)&L1[4] = *(const float4*)(bc + 4);
            if (r >= 2) {
                *(float4*)&L0[0] = *(const float4*)(bc - ILST);
                *(float4*)&L0[4] = *(const float4*)(bc - ILST + 4);
            } else {
                ldg8(L0, xin, ty0 - 3, tx0 - 4 + c0);
            }
            if (r <= AROWS - 1) {
                *(float4*)&L2[0] = *(const float4*)(bc + ILST);
                *(float4*)&L2[4] = *(const float4*)(bc + ILST + 4);
            } else {
                ldg8(L2, xin, ty0 + 34, tx0 - 4 + c0);
            }
        } else {
            const float* b0 = prev + (r - 2) * ILST + c0;
            *(float4*)&L0[0] = *(const float4*)(b0);
            *(float4*)&L1[0] = *(const float4*)(b0 + ILST);
            *(float4*)&L2[0] = *(const float4*)(b0 + 2 * ILST);
            *(float2*)&L0[4] = *(const float2*)(b0 + 4);
            *(float2*)&L1[4] = *(const float2*)(b0 + ILST + 4);
            *(float2*)&L2[4] = *(const float2*)(b0 + 2 * ILST + 4);
        }

        float acc[4] = {0.f, 0.f, 0.f, 0.f};
#pragma unroll
        for (int k = 0; k < 8; ++k) {
            const float w0 = Wt[9*k+0], w1 = Wt[9*k+1], w2 = Wt[9*k+2];
            const float w3 = Wt[9*k+3], w4 = Wt[9*k+4], w5 = Wt[9*k+5];
            const float w6 = Wt[9*k+6], w7 = Wt[9*k+7], w8 = Wt[9*k+8];
            const float bk = bt[k];
#pragma unroll
            for (int i = 0; i < 4; ++i) {
                float d = bk;
                d = fmaf(w0, L0[WOFF+i],   d);
                d = fmaf(w1, L0[WOFF+i+1], d);
                d = fmaf(w2, L0[WOFF+i+2], d);
                d = fmaf(w3, L1[WOFF+i],   d);
                d = fmaf(w4, L1[WOFF+i+1], d);
                d = fmaf(w5, L1[WOFF+i+2], d);
                d = fmaf(w6, L2[WOFF+i],   d);
                d = fmaf(w7, L2[WOFF+i+1], d);
                d = fmaf(w8, L2[WOFF+i+2], d);
                acc[i] = gd_acc(d, acc[i]);
            }
        }

        float4 v;
        v.x = L1[WOFF+1] - acc[0] * 0.125f;
        v.y = L1[WOFF+2] - acc[1] * 0.125f;
        v.z = L1[WOFF+3] - acc[2] * 0.125f;
        v.w = L1[WOFF+4] - acc[3] * 0.125f;

        const int gy = ty0 - 3 + r;
        if (TO_GLOBAL) {
            // step3: always fully interior to the image
            *(float4*)&gout[gy * IMG + tx0 + c0] = v;
        } else {
            // zero out-of-image pixels so the next step sees SAME zero padding
            const bool ry  = (unsigned)gy < (unsigned)IMG;
            const int  gx0 = xoff + c0;
            v.x = (ry && (unsigned)(gx0 + 0) < (unsigned)IMG) ? v.x : 0.f;
            v.y = (ry && (unsigned)(gx0 + 1) < (unsigned)IMG) ? v.y : 0.f;
            v.z = (ry && (unsigned)(gx0 + 2) < (unsigned)IMG) ? v.z : 0.f;
            v.w = (ry && (unsigned)(gx0 + 3) < (unsigned)IMG) ? v.w : 0.f;
            *(float4*)&cur[(r - 1) * OLST + c0] = v;
        }
    }
}

__global__ __launch_bounds__(NTHR) void deep_ad_fused8(
    const float* __restrict__ x, const float* __restrict__ W,
    const float* __restrict__ b, float* __restrict__ out)
{
    __shared__ float A [AROWS * LSTA];       // 2592 floats
    __shared__ float Bs[AROWS * LSTB + 2];   // 2450 floats (pad: step2 tail float2)

    const int tid = threadIdx.x;
    const int tx0 = blockIdx.x * TX;
    const int ty0 = blockIdx.y * TY;
    const float* xin  = x   + (size_t)blockIdx.z * (IMG * IMG);
    float*       gout = out + (size_t)blockIdx.z * (IMG * IMG);

    // ---- stage orig rows 1..36 into A (zeros outside image) ----
    {
        float4 sv[3];
#pragma unroll
        for (int q = 0; q < 3; ++q) {
            const int item = tid + NTHR * q;
            float4 v = {0.f, 0.f, 0.f, 0.f};
            if (item < NSTAGE) {
                const int rr = item / 18, jj = item - rr * 18;
                const int gy = ty0 - 2 + rr;        // orig row rr+1
                const int gx = tx0 - 4 + 4 * jj;    // float4 fully in or out
                if ((unsigned)gy < (unsigned)IMG && (unsigned)gx < (unsigned)IMG)
                    v = *(const float4*)(xin + gy * IMG + gx);
            }
            sv[q] = v;
        }
#pragma unroll
        for (int q = 0; q < 3; ++q) {
            const int item = tid + NTHR * q;
            if (item < NSTAGE) *(float4*)&A[item * 4] = sv[q];
        }
    }
    __syncthreads();

    // step1: orig rows 1..36 -> B rows 0..35 (68 cols)
    diffuse_step<1, 36, 1, 17, LSTA, LSTB, true,  false>(
        A,  Bs, W,       b,      xin, tx0 - 2, ty0, tx0, tid, nullptr);
    __syncthreads();
    // step2: B -> A rows 1..34 (step2-out row r at A[r-1])
    diffuse_step<0, 34, 2, 17, LSTB, LSTA, false, false>(
        Bs, A,  W + 72,  b + 8,  xin, tx0 - 1, ty0, tx0, tid, nullptr);
    __syncthreads();
    // step3: A -> global 64x32 tile
    diffuse_step<0, 32, 3, 16, LSTA, 0,    false, true >(
        A, nullptr, W + 144, b + 16, xin, 0, ty0, tx0, tid, gout);
}

extern "C" void kernel_launch(void* const* d_in, const int* in_sizes, int n_in,
                              void* d_out, int out_size, void* d_ws, size_t ws_size,
                              hipStream_t stream)
{
    const float* x = (const float*)d_in[0];
    const float* W = (const float*)d_in[1];  // [3,8,1,3,3]
    const float* b = (const float*)d_in[2];  // [3,8]
    float* out = (float*)d_out;
    const int N = in_sizes[0] / (IMG * IMG); // 16

    dim3 grid(IMG / TX, IMG / TY, N);        // (8, 16, 16) = 2048 blocks
    deep_ad_fused8<<<grid, NTHR, 0, stream>>>(x, W, b, out);
}